// Round 9
// baseline (1117.038 us; speedup 1.0000x reference)
//
#include <hip/hip_runtime.h>
#include <cstdint>
#include <cstddef>

// ---------------- problem constants (fixed by setup_inputs) ----------------
static constexpr int D_IN = 784;
static constexpr int H1   = 2048;
static constexpr int H2   = 10;
static constexpr int KK   = 10;
static constexpr int UU   = 2832;   // D_IN + H1
static constexpr int LL   = 128;
static constexpr int BB   = 1024;
static constexpr int TT   = 20;
static constexpr int HALF = BB * D_IN / 2;   // 401408 = 512*784
static constexpr int NCH  = 25;              // K chunks of 32 (784 -> 800 padded)

typedef int v4i  __attribute__((ext_vector_type(4)));
typedef int v16i __attribute__((ext_vector_type(16)));

// ---------------- JAX threefry2x32 (20 rounds), bit-exact ----------------
__device__ __forceinline__ uint32_t rotl32(uint32_t x, int d) {
  return (x << d) | (x >> (32 - d));
}
__device__ __forceinline__ void threefry2x32(uint32_t k0, uint32_t k1,
                                             uint32_t& x0, uint32_t& x1) {
  uint32_t ks2 = k0 ^ k1 ^ 0x1BD11BDAu;
  x0 += k0; x1 += k1;
#define TF_R(r) { x0 += x1; x1 = rotl32(x1, (r)); x1 ^= x0; }
  TF_R(13) TF_R(15) TF_R(26) TF_R(6)
  x0 += k1;  x1 += ks2 + 1u;
  TF_R(17) TF_R(29) TF_R(16) TF_R(24)
  x0 += ks2; x1 += k0 + 2u;
  TF_R(13) TF_R(15) TF_R(26) TF_R(6)
  x0 += k0;  x1 += k1 + 3u;
  TF_R(17) TF_R(29) TF_R(16) TF_R(24)
  x0 += k1;  x1 += ks2 + 4u;
  TF_R(13) TF_R(15) TF_R(26) TF_R(6)
  x0 += ks2; x1 += k0 + 5u;
#undef TF_R
}
__device__ __forceinline__ float bits_to_unif(uint32_t b) {
  uint32_t fb = (b >> 9) | 0x3F800000u;
  return __uint_as_float(fb) - 1.0f;
}

// ---------------- block-wide 3-way fp64 reduction + atomic ----------------
__device__ __forceinline__ double wave_red(double v) {
  #pragma unroll
  for (int off = 32; off > 0; off >>= 1) v += __shfl_down(v, off, 64);
  return v;
}
__device__ __forceinline__ void block_reduce3(double s0, double s1, double s2,
                                              double* gacc) {
  __shared__ double lds[3][4];
  int lane = threadIdx.x & 63, w = threadIdx.x >> 6;
  s0 = wave_red(s0); s1 = wave_red(s1); s2 = wave_red(s2);
  if (lane == 0) { lds[0][w] = s0; lds[1][w] = s1; lds[2][w] = s2; }
  __syncthreads();
  if (threadIdx.x == 0) {
    double t0 = 0, t1 = 0, t2 = 0;
    #pragma unroll
    for (int i = 0; i < 4; i++) { t0 += lds[0][i]; t1 += lds[1][i]; t2 += lds[2][i]; }
    atomicAdd(&gacc[0], t0); atomicAdd(&gacc[1], t1); atomicAdd(&gacc[2], t2);
  }
}

// ---------------- pre-kernel: val1/val2 (one wave per (k,u), ballot) ----------
__global__ __launch_bounds__(256)
void precompute_vals(const float* __restrict__ vec, const int* __restrict__ cnt,
                     float* __restrict__ v1, float* __restrict__ v2) {
  int gw = (blockIdx.x * 256 + threadIdx.x) >> 6;
  int lane = threadIdx.x & 63;
  if (gw >= KK * UU) return;
  const float* p = vec + (size_t)gw * LL;
  float a = p[lane];
  float b = p[lane + 64];
  unsigned long long mlo = __ballot(a != 0.0f);
  unsigned long long mhi = __ballot(b != 0.0f);
  if (lane == 0) {
    int u = gw % UU;
    int c = cnt[gw];
    int last = mhi ? (127 - __builtin_clzll(mhi))
                   : (mlo ? (63 - __builtin_clzll(mlo)) : -1);
    if (c > 0) {
      if (last >= 0) atomicAdd(&v1[u], (float)(last - 1));
      atomicAdd(&v2[u], (float)c);
    }
  }
}

// ---------------- pre-kernel: W1 -> 5 signed base-256 int8 limbs ----------------
// W1L entry index: ((ntile*NCH + chunk)*5 + limb)*64 + lane  (16 B each)
// lane mapping: n = ntile*32 + (lane&31), k = chunk*32 + (lane>>5)*16 + j
__global__ __launch_bounds__(256)
void make_limbs(const float* __restrict__ W1, v4i* __restrict__ W1L) {
  int tid = blockIdx.x * 256 + threadIdx.x;   // 64*NCH*64 = 102400
  int lane = tid & 63;
  int tc = tid >> 6;                           // ntile*NCH + chunk
  int n = ((tc / NCH) << 5) + (lane & 31);
  int chunk = tc % NCH;
  int k0 = chunk * 32 + (lane >> 5) * 16;
  union { v4i v; signed char b[16]; } d[5];
  #pragma unroll
  for (int j = 0; j < 16; j++) {
    long long F = 0;
    int k = k0 + j;
    if (k < D_IN) {
      double w = (double)W1[(size_t)n * D_IN + k];
      F = llround(w * 0x1p40);
    }
    #pragma unroll
    for (int l = 0; l < 5; l++) {
      int dig = (int)((F + 128) & 255) - 128;
      d[l].b[j] = (signed char)dig;
      F = (F - dig) >> 8;
    }
  }
  #pragma unroll
  for (int l = 0; l < 5; l++) W1L[(size_t)(tc * 5 + l) * 64 + lane] = d[l].v;
}

// ---------------- spike generation, A-fragment order, + a1/a2/cs terms ----------
// XA entry index: (mtile*NCH + chunk)*64 + lane
// lane mapping: m = mtile*32 + (lane&31), k = chunk*32 + (lane>>5)*16 + j
__device__ __forceinline__ void gen_wave(int gw, int t,
    const float* __restrict__ input, v4i* __restrict__ XA,
    const float* __restrict__ v1, const float* __restrict__ v2,
    double& s0, double& s1, double& s2) {
  int lane = threadIdx.x & 63;
  int mtile = gw / NCH, chunk = gw - mtile * NCH;   // mtile in [0,16): m < 512
  int m = (mtile << 5) + (lane & 31);
  int k0 = chunk * 32 + (lane >> 5) * 16;
  uint32_t f0 = 0u, f1 = (uint32_t)t;
  threefry2x32(0u, 42u, f0, f1);
  union { v4i v; unsigned char b[16]; } r0, r1;
  s0 = 0; s1 = 0; s2 = 0;
  if (k0 < D_IN) {   // 784 = 24*32+16: only chunk24/half1 is pad
    #pragma unroll
    for (int j = 0; j < 16; j++) {
      int k = k0 + j;
      uint32_t c0 = (uint32_t)(m * D_IN + k), c1 = c0 + (uint32_t)HALF;
      threefry2x32(f0, f1, c0, c1);
      float u0 = bits_to_unif(c0), u1 = bits_to_unif(c1);
      float i0 = input[(size_t)m * D_IN + k];
      float i1 = input[(size_t)(m + 512) * D_IN + k];
      unsigned char x0 = (i0 > u0) ? 1 : 0;
      unsigned char x1 = (i1 > u1) ? 1 : 0;
      r0.b[j] = x0; r1.b[j] = x1;
      double xsum = (double)(x0 + x1);
      s0 += xsum * (double)v1[k];
      s1 += xsum * (double)v2[k];
      s2 += xsum;
    }
  } else {
    r0.v = (v4i){0, 0, 0, 0};
    r1.v = (v4i){0, 0, 0, 0};
  }
  XA[(size_t)(mtile * NCH + chunk) * 64 + lane] = r0.v;
  XA[(size_t)((mtile + 16) * NCH + chunk) * 64 + lane] = r1.v;   // partner m+512
}

__global__ __launch_bounds__(256)
void gen0(const float* __restrict__ input, v4i* __restrict__ XA,
          const float* __restrict__ v1, const float* __restrict__ v2,
          double* __restrict__ gacc) {
  int gw = blockIdx.x * 4 + (threadIdx.x >> 6);    // 400 waves
  double s0, s1, s2;
  gen_wave(gw, 0, input, XA, v1, v2, s0, s1, s2);
  block_reduce3(s0, s1, s2, gacc);
}

// ---------------- h1 update: 5-limb i8 MFMA GEMM, wave tile 64m x 32n ----------
// Block = 4 waves -> 128m x 64n. Grid (32 n-blocks, 8 m-blocks): all m-blocks of
// one n-panel share an XCD (ids = bx mod 8) -> W1L panel is L2-resident.
// Depth-2 software prefetch: per iter 10 MFMAs (~90 cy) overlap 7 in-flight
// loads from the iteration before last (~200-300 cy L2 latency).
__global__ __launch_bounds__(256, 1)
void step_h1(const v4i* __restrict__ XA, const v4i* __restrict__ W1L,
             const float* __restrict__ b1, double* __restrict__ h1m,
             unsigned char* __restrict__ h1s, const float* __restrict__ v1,
             const float* __restrict__ v2, double* __restrict__ gacc) {
  int lane = threadIdx.x & 63, wv = threadIdx.x >> 6;
  int ntile = blockIdx.x * 2 + (wv & 1);           // [0,64)
  int mt0   = blockIdx.y * 4 + (wv >> 1) * 2;      // mtiles mt0, mt0+1 in [0,32)
  const v4i* a0p = XA + (size_t)mt0 * NCH * 64 + lane;
  const v4i* a1p = XA + (size_t)(mt0 + 1) * NCH * 64 + lane;
  const v4i* bp  = W1L + (size_t)ntile * NCH * 5 * 64 + lane;

  v16i c00 = {}, c10 = {}, c20 = {}, c30 = {}, c40 = {};   // limb x mhalf0
  v16i c01 = {}, c11 = {}, c21 = {}, c31 = {}, c41 = {};   // limb x mhalf1

  // pipeline: current (c), next (n), fetch (f = c+2, index clamped: chunk 24
  // re-loaded harmlessly instead of branching/undef)
  v4i cA0 = a0p[0], cA1 = a1p[0];
  v4i cB0 = bp[0], cB1 = bp[64], cB2 = bp[128], cB3 = bp[192], cB4 = bp[256];
  v4i nA0 = a0p[64], nA1 = a1p[64];
  v4i nB0 = bp[320], nB1 = bp[384], nB2 = bp[448], nB3 = bp[512], nB4 = bp[576];

  #pragma unroll 1
  for (int c = 0; c < NCH; c++) {
    int cc = c + 2 < NCH ? c + 2 : NCH - 1;
    v4i fA0 = a0p[cc * 64];
    v4i fA1 = a1p[cc * 64];
    const v4i* br = bp + (size_t)cc * 5 * 64;
    v4i fB0 = br[0], fB1 = br[64], fB2 = br[128], fB3 = br[192], fB4 = br[256];

    c00 = __builtin_amdgcn_mfma_i32_32x32x32_i8(cA0, cB0, c00, 0, 0, 0);
    c01 = __builtin_amdgcn_mfma_i32_32x32x32_i8(cA1, cB0, c01, 0, 0, 0);
    c10 = __builtin_amdgcn_mfma_i32_32x32x32_i8(cA0, cB1, c10, 0, 0, 0);
    c11 = __builtin_amdgcn_mfma_i32_32x32x32_i8(cA1, cB1, c11, 0, 0, 0);
    c20 = __builtin_amdgcn_mfma_i32_32x32x32_i8(cA0, cB2, c20, 0, 0, 0);
    c21 = __builtin_amdgcn_mfma_i32_32x32x32_i8(cA1, cB2, c21, 0, 0, 0);
    c30 = __builtin_amdgcn_mfma_i32_32x32x32_i8(cA0, cB3, c30, 0, 0, 0);
    c31 = __builtin_amdgcn_mfma_i32_32x32x32_i8(cA1, cB3, c31, 0, 0, 0);
    c40 = __builtin_amdgcn_mfma_i32_32x32x32_i8(cA0, cB4, c40, 0, 0, 0);
    c41 = __builtin_amdgcn_mfma_i32_32x32x32_i8(cA1, cB4, c41, 0, 0, 0);

    cA0 = nA0; cA1 = nA1;
    cB0 = nB0; cB1 = nB1; cB2 = nB2; cB3 = nB3; cB4 = nB4;
    nA0 = fA0; nA1 = fA1;
    nB0 = fB0; nB1 = fB1; nB2 = fB2; nB3 = fB3; nB4 = fB4;
  }

  // epilogue: C/D layout (32x32): col=lane&31, row=(r&3)+8*(r>>2)+4*(lane>>5)
  int col = lane & 31;
  int rbase = (lane >> 5) * 4;
  int gn = (ntile << 5) + col;
  double bias = (double)b1[gn];
  double v1n = (double)v1[D_IN + gn], v2n = (double)v2[D_IN + gn];
  double s0 = 0, s1 = 0, s2 = 0;
  #pragma unroll
  for (int mh = 0; mh < 2; mh++) {
    const v16i& q0 = mh ? c01 : c00;
    const v16i& q1 = mh ? c11 : c10;
    const v16i& q2 = mh ? c21 : c20;
    const v16i& q3 = mh ? c31 : c30;
    const v16i& q4 = mh ? c41 : c40;
    int gmb = (mt0 + mh) << 5;
    #pragma unroll
    for (int r = 0; r < 16; r++) {
      int row = (r & 3) + 8 * (r >> 2) + rbase;
      int gm = gmb + row;
      double dot = ((((double)q4[r] * 256.0 + (double)q3[r]) * 256.0
                     + (double)q2[r]) * 256.0 + (double)q1[r]) * 256.0 + (double)q0[r];
      dot *= 0x1p-40;
      size_t idx = (size_t)gm * H1 + gn;
      double mprev = h1m[idx];
      double sprev = (mprev > 0.5) ? 1.0 : 0.0;
      double mnew = mprev * 0.2 * (1.0 - sprev) + dot + bias;
      bool s = (mnew > 0.5);
      h1m[idx] = mnew;
      h1s[idx] = s ? 1 : 0;
      if (s) { s0 += v1n; s1 += v2n; s2 += 1.0; }
    }
  }
  block_reduce3(s0, s1, s2, gacc);
}

// ---------------- fused: h2 update (blocks 0..255) + gen_x(t+1) (blocks 256+) ----
// W2 read row-major: lane-consecutive i -> coalesced (r4's W2T gather was ~40x
// L1 line amplification).
__global__ __launch_bounds__(256)
void fused_h2_genx(const unsigned char* __restrict__ h1s,
                   const float* __restrict__ W2, const float* __restrict__ b2,
                   double* __restrict__ h2m, float* __restrict__ h2s,
                   float* __restrict__ h2sum, double* __restrict__ gacc,
                   float* __restrict__ out, const float* __restrict__ input,
                   v4i* __restrict__ XA, const float* __restrict__ v1,
                   const float* __restrict__ v2, int tnext, int last) {
  if (blockIdx.x < 256) {
    int lane = threadIdx.x & 63, wv = threadIdx.x >> 6;
    int b = blockIdx.x * 4 + wv;
    const unsigned char* hrow = h1s + (size_t)b * H1;
    double p[H2] = {};
    #pragma unroll 1
    for (int i = lane; i < H1; i += 64) {
      if (hrow[i]) {
        #pragma unroll
        for (int j = 0; j < H2; j++) p[j] += (double)W2[j * H1 + i];  // coalesced
      }
    }
    #pragma unroll
    for (int j = 0; j < H2; j++) {
      double v = p[j];
      #pragma unroll
      for (int off = 32; off > 0; off >>= 1) v += __shfl_xor(v, off, 64);
      p[j] = v;
    }
    if (lane < H2) {
      double red = 0;
      #pragma unroll
      for (int j = 0; j < H2; j++) red = (lane == j) ? p[j] : red;
      size_t idx = (size_t)b * H2 + lane;
      double m = h2m[idx] * 0.2 * (1.0 - (double)h2s[idx]) + red + (double)b2[lane];
      float s = (m > 0.5) ? 1.0f : 0.0f;
      float ns = h2sum[idx] + s;
      h2m[idx] = m; h2s[idx] = s; h2sum[idx] = ns;
      if (last) out[idx] = (float)((double)ns / (double)TT);
    }
  } else {
    if (tnext >= TT) return;
    int gw = (blockIdx.x - 256) * 4 + (threadIdx.x >> 6);
    double s0, s1, s2;
    gen_wave(gw, tnext, input, XA, v1, v2, s0, s1, s2);
    block_reduce3(s0, s1, s2, gacc);
  }
}

// ---------------- post-kernel: scalar readout (boundary-separated from gacc) ----
__global__ void finalize_scalars(const double* __restrict__ gacc,
                                 float* __restrict__ out) {
  if (threadIdx.x < 3)
    out[(size_t)BB * H2 + threadIdx.x] = (float)gacc[threadIdx.x];
}

// ---------------- launch ----------------
extern "C" void kernel_launch(void* const* d_in, const int* in_sizes, int n_in,
                              void* d_out, int out_size, void* d_ws, size_t ws_size,
                              hipStream_t stream) {
  const float* input = (const float*)d_in[0];
  const float* W1    = (const float*)d_in[1];
  const float* b1    = (const float*)d_in[2];
  const float* W2    = (const float*)d_in[3];
  const float* b2    = (const float*)d_in[4];
  const float* cmv   = (const float*)d_in[5];
  const int*   cmc   = (const int*)d_in[6];

  char* base = (char*)d_ws;
  // zeroed region
  double* h1m  = (double*)(base + 0);                  // 16,777,216 B
  double* h2m  = (double*)(base + 16777216);           //     81,920 B
  double* gacc = (double*)(base + 16859136);           //         64 B
  float*  h2s  = (float*)(base + 16859200);            //     40,960 B
  float*  h2sm = (float*)(base + 16900160);            //     40,960 B
  float*  v1   = (float*)(base + 16941120);            //     11,328 B
  float*  v2   = (float*)(base + 16952448);            //     11,328 B
  const size_t ZERO_BYTES = 16963776;
  // non-zeroed region (every element written before read)
  unsigned char* h1s = (unsigned char*)(base + 16963776); // 2,097,152 B
  v4i*    XA   = (v4i*)(base + 19060928);              //    819,200 B
  v4i*    W1L  = (v4i*)(base + 19880128);              //  8,192,000 B (end 28,072,128)

  hipMemsetAsync(d_ws, 0, ZERO_BYTES, stream);

  precompute_vals<<<(KK * UU) / 4, 256, 0, stream>>>(cmv, cmc, v1, v2);
  make_limbs<<<(64 * NCH * 64) / 256, 256, 0, stream>>>(W1, W1L);
  gen0<<<100, 256, 0, stream>>>(input, XA, v1, v2, gacc);

  for (int t = 0; t < TT; t++) {
    step_h1<<<dim3(32, 8), 256, 0, stream>>>(XA, W1L, b1, h1m, h1s, v1, v2, gacc);
    fused_h2_genx<<<356, 256, 0, stream>>>(h1s, W2, b2, h2m, h2s, h2sm, gacc,
                                           (float*)d_out, input, XA, v1, v2,
                                           t + 1, (t == TT - 1) ? 1 : 0);
  }

  finalize_scalars<<<1, 64, 0, stream>>>(gacc, (float*)d_out);
}